// Round 20
// baseline (461.395 us; speedup 1.0000x reference)
//
#include <hip/hip_runtime.h>

typedef __bf16 bf16x8 __attribute__((ext_vector_type(8)));
typedef float f32x4 __attribute__((ext_vector_type(4)));
typedef unsigned int uint32x4 __attribute__((ext_vector_type(4)));

#define DD 256
#define VV 1024
#define BN 16
#define KC1 36   // extended-K chunks of 8 (288/8): 32 data + c2 + zeros
#define WVA 8    // waves per block

__device__ __forceinline__ unsigned short f2bf(float f) {
    unsigned int b = __float_as_uint(f);
    b += 0x7FFFu + ((b >> 16) & 1u);
    return (unsigned short)(b >> 16);
}

// async global->LDS, 16B per lane. LDS dst must be WAVE-UNIFORM base
// (HW adds lane*16); global src is per-lane.
typedef __attribute__((address_space(3))) unsigned int lds_uint;
typedef __attribute__((address_space(1))) const unsigned int glb_uint;
__device__ __forceinline__ void dma16(const float* g, float* l) {
    __builtin_amdgcn_global_load_lds((glb_uint*)g, (lds_uint*)l, 16, 0, 0);
}

// Prep: fragment-major, sigma-permuted codebook layouts (verified R8+).
// sigma: element d -> kc = (d>>5)*4 + ((d>>2)&3), j = (d&3) + ((d>>4)&1)*4.
__global__ __launch_bounds__(256) void vq_prep_kernel(
    const float* __restrict__ cb,
    unsigned short* __restrict__ cbA,   // [V/16][KC1][16][8]
    unsigned short* __restrict__ cbB)   // [D/16][128][16][8]
{
    int v = blockIdx.x;
    int t = threadIdx.x;
    float val = cb[(size_t)v * DD + t];
    unsigned short h = f2bf(val);
    const int vtile = v >> 4, vi = v & 15;
    const int kc_t = (t >> 5) * 4 + ((t >> 2) & 3);
    const int j_t  = (t & 3) + ((t >> 4) & 1) * 4;
    cbA[(((size_t)vtile * KC1 + kc_t) * 16 + vi) * 8 + j_t] = h;
    const int kcv = (v >> 5) * 4 + ((v >> 2) & 3);
    const int jv  = (v & 3) + ((v >> 4) & 1) * 4;
    cbB[(((size_t)(t >> 4) * 128 + kcv) * 16 + (t & 15)) * 8 + jv] = h;

    float p = val * val;
#pragma unroll
    for (int d = 1; d < 64; d <<= 1) p += __shfl_xor(p, d);
    __shared__ float ps[4];
    if ((t & 63) == 0) ps[t >> 6] = p;
    __syncthreads();
    if (t < 32) {
        float c2 = ps[0] + ps[1] + ps[2] + ps[3];
        float m = -0.5f * c2;
        unsigned short hi = f2bf(m);
        float hif = __uint_as_float((unsigned int)hi << 16);
        unsigned short lo = f2bf(m - hif);
        unsigned short o = (t == 0) ? hi : ((t == 1) ? lo : (unsigned short)0);
        cbA[(((size_t)vtile * KC1 + 32 + (t >> 3)) * 16 + vi) * 8 + (t & 7)] = o;
    }
}

// ABLATION build of the R18 kernel: GEMM1 is executed TWICE (second pass over
// a shifted cbA tile set, results kept alive then discarded). dur delta vs
// R18 == marginal cost of one GEMM1 (72 L2 loads + 72 MFMAs per wave).
__global__ __launch_bounds__(512, 4) void vq_main_kernel(
    const float* __restrict__ x,          // [N][D]
    const float* __restrict__ gum,        // [N][V]
    const unsigned short* __restrict__ cbA,
    const unsigned short* __restrict__ cbB,
    float* __restrict__ out_q,            // [N][D]
    float* __restrict__ out_p)            // [N][V]
{
    __shared__ __align__(16) float xbuf[BN * DD];      // 16 KB
    __shared__ __align__(16) float gbuf[WVA * 1024];   // 32 KB; later: prob bf16
    __shared__ float sred[WVA * BN];                   // 512 B

    const int tid  = threadIdx.x;
    const int wave = tid >> 6;    // 0..7
    const int lane = tid & 63;
    const int lrow = (lane >> 4) & 3;
    const int lcol = lane & 15;
    const int row0 = blockIdx.x * BN;
    const int laneoff = lrow * 128 + lcol * 8;
    float* greg = &gbuf[wave * 1024];   // this wave's 4 KB gumbel region

    // ---- DMA issue: x rows (2/wave) then own gumbel half-0 (4 x 1KB) ----
#pragma unroll
    for (int h = 0; h < 2; ++h) {
        const int r = wave * 2 + h;
        dma16(x + (size_t)(row0 + r) * DD + (((lane ^ (r & 7)) & 63) << 2),
              &xbuf[r * DD]);
    }
#pragma unroll
    for (int d = 0; d < 4; ++d) {
        const int r = d * 4 + (lane >> 4);
        dma16(gum + (size_t)(row0 + r) * VV + wave * 64 +
                  ((((lane & 15) ^ (r & 7))) << 2),
              &greg[d * 256]);
    }
    asm volatile("s_waitcnt vmcnt(4)" ::: "memory");
    __builtin_amdgcn_sched_barrier(0);
    __builtin_amdgcn_s_barrier();

    // ---- afr from xbuf (sigma slots) + x2 ----
    bf16x8 afr[9];
    float x2 = 0.f;
#pragma unroll
    for (int kt = 0; kt < 8; ++kt) {
        const int g1 = (kt * 8 + lrow) ^ (lcol & 7);
        const int g2 = (kt * 8 + lrow + 4) ^ (lcol & 7);
        f32x4 a = *reinterpret_cast<const f32x4*>(&xbuf[lcol * DD + g1 * 4]);
        f32x4 b = *reinterpret_cast<const f32x4*>(&xbuf[lcol * DD + g2 * 4]);
        bf16x8 fr;
#pragma unroll
        for (int j = 0; j < 4; ++j) {
            x2 += a[j] * a[j] + b[j] * b[j];
            fr[j]     = (__bf16)a[j];
            fr[j + 4] = (__bf16)b[j];
        }
        afr[kt] = fr;
    }
    x2 += __shfl_xor(x2, 16);
    x2 += __shfl_xor(x2, 32);
    {
        uint32x4 w = {0u, 0u, 0u, 0u};
        if (lrow == 0) w[0] = 0x3F803F80u;  // bf16 1.0 pair at c2 slots
        afr[8] = __builtin_bit_cast(bf16x8, w);
    }

    // ---- GEMM1 (real): acc[nt]: v = (nt>>2)*512 + wave*64 + (nt&3)*16 ... ----
    f32x4 acc[8];
#pragma unroll
    for (int nt = 0; nt < 8; ++nt) acc[nt] = (f32x4){0.f, 0.f, 0.f, 0.f};
#pragma unroll
    for (int nt = 0; nt < 8; ++nt) {
        const int vt = (nt >> 2) * 32 + wave * 4 + (nt & 3);
        const unsigned short* ap = cbA + (size_t)vt * (KC1 * 128) + laneoff;
#pragma unroll
        for (int kt = 0; kt < 9; ++kt) {
            bf16x8 cfr = __builtin_bit_cast(bf16x8,
                *reinterpret_cast<const uint32x4*>(ap + kt * 512));
            acc[nt] = __builtin_amdgcn_mfma_f32_16x16x32_bf16(cfr, afr[kt], acc[nt], 0, 0, 0);
        }
    }

    // ---- GEMM1 (ablation double): shifted tiles (wave+1)&7 -> not CSE-able.
    // Same load count, same MFMA count; results kept alive then discarded.
    {
        f32x4 acc2[8];
#pragma unroll
        for (int nt = 0; nt < 8; ++nt) acc2[nt] = (f32x4){0.f, 0.f, 0.f, 0.f};
#pragma unroll
        for (int nt = 0; nt < 8; ++nt) {
            const int vt = (nt >> 2) * 32 + ((wave + 1) & 7) * 4 + (nt & 3);
            const unsigned short* ap = cbA + (size_t)vt * (KC1 * 128) + laneoff;
#pragma unroll
            for (int kt = 0; kt < 9; ++kt) {
                bf16x8 cfr = __builtin_bit_cast(bf16x8,
                    *reinterpret_cast<const uint32x4*>(ap + kt * 512));
                acc2[nt] = __builtin_amdgcn_mfma_f32_16x16x32_bf16(cfr, afr[kt], acc2[nt], 0, 0, 0);
            }
        }
#pragma unroll
        for (int nt = 0; nt < 8; ++nt)
            asm volatile("" :: "v"(acc2[nt][0]), "v"(acc2[nt][1]),
                              "v"(acc2[nt][2]), "v"(acc2[nt][3]));
    }

    // own gumbel half-0 landed (wave-local wait, no barrier)
    asm volatile("s_waitcnt vmcnt(0)" ::: "memory");
    __builtin_amdgcn_sched_barrier(0);

    // ---- u4 half-0 reads ----
    f32x4 u4[4];
#pragma unroll
    for (int nt = 0; nt < 4; ++nt) {
        const int s = (nt * 4 + lrow) ^ (lcol & 7);
        u4[nt] = *reinterpret_cast<const f32x4*>(&greg[lcol * 64 + s * 4]);
    }
    asm volatile("s_waitcnt lgkmcnt(0)" ::: "memory");
    __builtin_amdgcn_sched_barrier(0);
#pragma unroll
    for (int d = 0; d < 4; ++d) {
        const int r = d * 4 + (lane >> 4);
        dma16(gum + (size_t)(row0 + r) * VV + 512 + wave * 64 +
                  ((((lane & 15) ^ (r & 7))) << 2),
              &greg[d * 256]);
    }

    // ---- softmax half-0 (hides half-1 DMA) ----
    float ss = 0.f;
#pragma unroll
    for (int nt = 0; nt < 4; ++nt) {
#pragma unroll
        for (int r = 0; r < 4; ++r) {
            float u = fminf(fmaxf(u4[nt][r], 1e-10f), 1.0f - 1e-10f);
            float l2u = __builtin_amdgcn_logf(u);
            float t = u - 1.0f;
            float pp = t * (1.0f + t * (-0.5f + t * (0.33333333f + t * (-0.25f + t * 0.2f))));
            float w = (u >= 0.984375f) ? -pp : (l2u * -0.69314718f);
            float l2w = __builtin_amdgcn_logf(w);
            float d2 = fmaxf(__builtin_fmaf(-2.0f, acc[nt][r], x2), 1e-12f);
            float dist = __builtin_amdgcn_sqrtf(d2);
            float lg2 = __builtin_fmaf(-0.72134752f, dist, -0.5f * l2w);
            float e = __builtin_amdgcn_exp2f(lg2);
            acc[nt][r] = e;
            ss += e;
        }
    }

    // own gumbel half-1 landed
    asm volatile("s_waitcnt vmcnt(0)" ::: "memory");
    __builtin_amdgcn_sched_barrier(0);
#pragma unroll
    for (int nt = 0; nt < 4; ++nt) {
        const int s = (nt * 4 + lrow) ^ (lcol & 7);
        u4[nt] = *reinterpret_cast<const f32x4*>(&greg[lcol * 64 + s * 4]);
    }
    // ---- softmax half-1 ----
#pragma unroll
    for (int nt = 0; nt < 4; ++nt) {
#pragma unroll
        for (int r = 0; r < 4; ++r) {
            float u = fminf(fmaxf(u4[nt][r], 1e-10f), 1.0f - 1e-10f);
            float l2u = __builtin_amdgcn_logf(u);
            float t = u - 1.0f;
            float pp = t * (1.0f + t * (-0.5f + t * (0.33333333f + t * (-0.25f + t * 0.2f))));
            float w = (u >= 0.984375f) ? -pp : (l2u * -0.69314718f);
            float l2w = __builtin_amdgcn_logf(w);
            float d2 = fmaxf(__builtin_fmaf(-2.0f, acc[nt + 4][r], x2), 1e-12f);
            float dist = __builtin_amdgcn_sqrtf(d2);
            float lg2 = __builtin_fmaf(-0.72134752f, dist, -0.5f * l2w);
            float e = __builtin_amdgcn_exp2f(lg2);
            acc[nt + 4][r] = e;
            ss += e;
        }
    }
    ss += __shfl_xor(ss, 16);
    ss += __shfl_xor(ss, 32);

    if (lane < 16) sred[wave * 16 + lane] = ss;
    __syncthreads();   // B2: sred visible; ALL waves done with gumbel reads

    float Z = 0.f;
#pragma unroll
    for (int w = 0; w < WVA; ++w) Z += sred[w * 16 + lcol];
    const float rinv = 1.0f / Z;

    // ---- normalize; prob -> gbuf as bf16 sigma-slot tile [16][1024] ----
    unsigned short* pb = reinterpret_cast<unsigned short*>(gbuf);
#pragma unroll
    for (int nt = 0; nt < 8; nt += 2) {
        const int G = (nt >> 2) * 16 + wave * 2 + ((nt & 3) >> 1);
        uint32x4 pk;
#pragma unroll
        for (int h = 0; h < 2; ++h) {
#pragma unroll
            for (int r = 0; r < 4; ++r) acc[nt + h][r] *= rinv;
            __bf16 b0 = (__bf16)acc[nt + h][0], b1 = (__bf16)acc[nt + h][1];
            __bf16 b2 = (__bf16)acc[nt + h][2], b3 = (__bf16)acc[nt + h][3];
            pk[2 * h]     = (unsigned int)__builtin_bit_cast(unsigned short, b0) |
                            ((unsigned int)__builtin_bit_cast(unsigned short, b1) << 16);
            pk[2 * h + 1] = (unsigned int)__builtin_bit_cast(unsigned short, b2) |
                            ((unsigned int)__builtin_bit_cast(unsigned short, b3) << 16);
        }
        const int s = G * 32 + lrow * 8;
        *reinterpret_cast<uint32x4*>(&pb[lcol * VV + (s ^ ((lcol & 7) << 3))]) = pk;
    }
    __syncthreads();   // B3: prob tile visible

    // ---- out_p stores issued first (fly under GEMM2) ----
    {
        float* oprow = out_p + (size_t)(row0 + lcol) * VV;
#pragma unroll
        for (int nt = 0; nt < 8; ++nt) {
            const int vbase = (nt >> 2) * 512 + wave * 64 + (nt & 3) * 16 + lrow * 4;
            *reinterpret_cast<float4*>(oprow + vbase) =
                (float4){acc[nt][0], acc[nt][1], acc[nt][2], acc[nt][3]};
        }
    }

    // ---- GEMM2: out_q[16][wave*32..+31] = prob[16][1024] @ cb ----
    f32x4 q[2];
    q[0] = (f32x4){0.f, 0.f, 0.f, 0.f};
    q[1] = (f32x4){0.f, 0.f, 0.f, 0.f};
    const unsigned short* bb0 = cbB + (size_t)(wave * 2) * 16384 + laneoff;
    const unsigned short* bb1 = bb0 + 16384;

#pragma unroll 4
    for (int kt = 0; kt < 32; ++kt) {
        bf16x8 pfr = __builtin_bit_cast(bf16x8,
            *reinterpret_cast<const uint32x4*>(
                &pb[lcol * VV + ((kt * 32 + lrow * 8) ^ ((lcol & 7) << 3))]));
        bf16x8 f0 = __builtin_bit_cast(bf16x8,
            *reinterpret_cast<const uint32x4*>(bb0 + kt * 512));
        bf16x8 f1 = __builtin_bit_cast(bf16x8,
            *reinterpret_cast<const uint32x4*>(bb1 + kt * 512));
        q[0] = __builtin_amdgcn_mfma_f32_16x16x32_bf16(pfr, f0, q[0], 0, 0, 0);
        q[1] = __builtin_amdgcn_mfma_f32_16x16x32_bf16(pfr, f1, q[1], 0, 0, 0);
    }

    // ---- out_q: C[row = row0+lrow*4+r][d = wave*32 + {0,16} + lcol] ----
    {
        float* qrow0 = out_q + (size_t)(row0 + lrow * 4) * DD + wave * 32 + lcol;
#pragma unroll
        for (int r = 0; r < 4; ++r) {
            float* qr = qrow0 + r * DD;
            qr[0]  = q[0][r];
            qr[16] = q[1][r];
        }
    }
}

extern "C" void kernel_launch(void* const* d_in, const int* in_sizes, int n_in,
                              void* d_out, int out_size, void* d_ws, size_t ws_size,
                              hipStream_t stream) {
    (void)in_sizes; (void)n_in; (void)out_size; (void)ws_size;
    const float* x   = (const float*)d_in[0];   // [16,4096,256]
    const float* cb  = (const float*)d_in[1];   // [1024,256]
    const float* gum = (const float*)d_in[2];   // [65536,1024]

    const int N = 16 * 4096;
    float* out_q = (float*)d_out;                       // [N][256]
    float* out_p = out_q + (size_t)N * DD;              // [N][1024]

    unsigned short* cbA = (unsigned short*)d_ws;        // 576 KB fragment-major
    unsigned short* cbB = cbA + (size_t)64 * KC1 * 128; // 512 KB fragment-major
    vq_prep_kernel<<<VV, 256, 0, stream>>>(cb, cbA, cbB);
    vq_main_kernel<<<N / BN, 512, 0, stream>>>(x, gum, cbA, cbB, out_q, out_p);
}

// Round 21
// 448.919 us; speedup vs baseline: 1.0278x; 1.0278x over previous
//
#include <hip/hip_runtime.h>

typedef __bf16 bf16x8 __attribute__((ext_vector_type(8)));
typedef float f32x4 __attribute__((ext_vector_type(4)));
typedef float f32x16 __attribute__((ext_vector_type(16)));
typedef unsigned int uint32x4 __attribute__((ext_vector_type(4)));

#define DD 256
#define VV 1024
#define BN 32    // rows per block
#define KCA 17   // cbA32 K-tiles of 16: 16 data + 1 (c2 fold)

__device__ __forceinline__ unsigned short f2bf(float f) {
    unsigned int b = __float_as_uint(f);
    b += 0x7FFFu + ((b >> 16) & 1u);
    return (unsigned short)(b >> 16);
}

typedef __attribute__((address_space(3))) unsigned int lds_uint;
typedef __attribute__((address_space(1))) const unsigned int glb_uint;
__device__ __forceinline__ void dma16(const float* g, float* l) {
    __builtin_amdgcn_global_load_lds((glb_uint*)g, (lds_uint*)l, 16, 0, 0);
}

// Prep: 32x32-MFMA fragment-major layouts.
// cbA32[vt][kt<17][l][j]: A-frag cb[v=vt*32+(l&31)][d=kt*16+(l>>5)*8+j]; kt=16
//   is the c2 tile (j=0: -c2/2 hi, j=1: lo at l=v&31; else 0).
// cbB32[dt][kt<64][l][j]: B-frag cb[v=kt*16+(l>>5)*8+j][d=dt*32+(l&31)].
__global__ __launch_bounds__(256) void vq_prep_kernel(
    const float* __restrict__ cb,
    unsigned short* __restrict__ cbA32,  // [32][17][64][8]
    unsigned short* __restrict__ cbB32)  // [8][64][64][8]
{
    const int v = blockIdx.x;
    const int t = threadIdx.x;
    float val = cb[(size_t)v * DD + t];
    unsigned short h = f2bf(val);
    cbA32[((size_t)((v >> 5) * KCA + (t >> 4)) * 64 +
           (v & 31) + 32 * ((t >> 3) & 1)) * 8 + (t & 7)] = h;
    cbB32[((size_t)((t >> 5) * 64 + (v >> 4)) * 64 +
           (t & 31) + 32 * ((v >> 3) & 1)) * 8 + (v & 7)] = h;

    float p = val * val;
#pragma unroll
    for (int d = 1; d < 64; d <<= 1) p += __shfl_xor(p, d);
    __shared__ float ps[4];
    if ((t & 63) == 0) ps[t >> 6] = p;
    __syncthreads();
    if (t < 16) {
        float c2 = ps[0] + ps[1] + ps[2] + ps[3];
        float m = -0.5f * c2;
        unsigned short hi = f2bf(m);
        float hif = __uint_as_float((unsigned int)hi << 16);
        unsigned short lo = f2bf(m - hif);
        const size_t tb = (size_t)((v >> 5) * KCA + 16) * 64;
        if (t < 8)
            cbA32[(tb + (v & 31)) * 8 + t] =
                (t == 0) ? hi : ((t == 1) ? lo : (unsigned short)0);
        else
            cbA32[(tb + 32 + (v & 31)) * 8 + (t - 8)] = 0;
    }
}

// Fused main, 32-row blocks, 16 waves, 32x32x16 MFMA (one codebook fragment
// feeds 32 rows -> per-CU codebook VMEM stream halved vs R18: the measured
// ~25 B/cy/CU TA wall from the R20 ablation).
__global__ __launch_bounds__(1024, 4) void vq_main_kernel(
    const float* __restrict__ x,          // [N][D]
    const float* __restrict__ gum,        // [N][V]
    const unsigned short* __restrict__ cbA32,
    const unsigned short* __restrict__ cbB32,
    float* __restrict__ out_q,            // [N][D]
    float* __restrict__ out_p)            // [N][V]
{
    __shared__ __align__(16) unsigned short xb16[16 * 64 * 8];  // 16 KB
    __shared__ __align__(16) float gbuf[16 * 1024];             // 64 KB; later pb
    __shared__ __align__(16) float xq[8 * 1024];                // 32 KB
    __shared__ float sred[16 * 32];                             // 2 KB
    __shared__ float sx2[32];

    const int tid  = threadIdx.x;
    const int w    = tid >> 6;     // 0..15
    const int lane = tid & 63;
    const int hi   = lane >> 5;
    const int rowc = lane & 31;    // this lane's output row (C col)
    const int row0 = blockIdx.x * BN;
    float* greg = &gbuf[w * 1024]; // this wave's 4 KB gumbel region

    // ---- gumbel DMA half-0 (v-tile vt = 2w) ----
#pragma unroll
    for (int d = 0; d < 4; ++d) {
        const int rr = d * 8 + (lane >> 3);
        dma16(gum + (size_t)(row0 + rr) * VV + (w * 2) * 32 +
                  4 * ((lane & 7) ^ ((lane >> 3) & 7)),
              &greg[d * 256]);
    }

    // ---- x load -> xb16 (B-frag layout) + x2 ----
    {
        const int xr = tid >> 5;   // 0..31
        const int c  = tid & 31;
        const float* xp = x + (size_t)(row0 + xr) * DD + c * 8;
        f32x4 a = *reinterpret_cast<const f32x4*>(xp);
        f32x4 b = *reinterpret_cast<const f32x4*>(xp + 4);
        float s = 0.f;
        bf16x8 fr;
#pragma unroll
        for (int j = 0; j < 4; ++j) {
            s += a[j] * a[j] + b[j] * b[j];
            fr[j]     = (__bf16)a[j];
            fr[j + 4] = (__bf16)b[j];
        }
#pragma unroll
        for (int d = 1; d < 32; d <<= 1) s += __shfl_xor(s, d);
        if ((lane & 31) == 0) sx2[xr] = s;
        *reinterpret_cast<uint32x4*>(
            &xb16[((c >> 1) * 64 + xr + 32 * (c & 1)) * 8]) =
            __builtin_bit_cast(uint32x4, fr);
    }
    // barrier: xb16 + sx2 visible; gumbel DMA stays in flight
    asm volatile("s_waitcnt lgkmcnt(0)" ::: "memory");
    __builtin_amdgcn_sched_barrier(0);
    __builtin_amdgcn_s_barrier();

    // ---- GEMM1: acc_t (t=0,1) = S[32 rows][vt=2w+t], K=272 ----
    f32x16 acc0, acc1;
#pragma unroll
    for (int i = 0; i < 16; ++i) { acc0[i] = 0.f; acc1[i] = 0.f; }
    const unsigned short* apA = cbA32 + ((size_t)(w * 2) * KCA * 64 + lane) * 8;
#pragma unroll
    for (int kt = 0; kt < 16; ++kt) {
        bf16x8 bfr = __builtin_bit_cast(bf16x8,
            *reinterpret_cast<const uint32x4*>(&xb16[(kt * 64 + lane) * 8]));
        bf16x8 c0 = __builtin_bit_cast(bf16x8,
            *reinterpret_cast<const uint32x4*>(apA + kt * 512));
        bf16x8 c1 = __builtin_bit_cast(bf16x8,
            *reinterpret_cast<const uint32x4*>(apA + KCA * 512 + kt * 512));
        acc0 = __builtin_amdgcn_mfma_f32_32x32x16_bf16(c0, bfr, acc0, 0, 0, 0);
        acc1 = __builtin_amdgcn_mfma_f32_32x32x16_bf16(c1, bfr, acc1, 0, 0, 0);
    }
    {   // c2 tile (kt=16): B = 1.0 at k-local 0,1 (lanes<32, j=0,1)
        uint32x4 wv = {0u, 0u, 0u, 0u};
        if (hi == 0) wv[0] = 0x3F803F80u;
        bf16x8 bfr = __builtin_bit_cast(bf16x8, wv);
        bf16x8 c0 = __builtin_bit_cast(bf16x8,
            *reinterpret_cast<const uint32x4*>(apA + 16 * 512));
        bf16x8 c1 = __builtin_bit_cast(bf16x8,
            *reinterpret_cast<const uint32x4*>(apA + KCA * 512 + 16 * 512));
        acc0 = __builtin_amdgcn_mfma_f32_32x32x16_bf16(c0, bfr, acc0, 0, 0, 0);
        acc1 = __builtin_amdgcn_mfma_f32_32x32x16_bf16(c1, bfr, acc1, 0, 0, 0);
    }

    const float x2 = sx2[rowc];

    // ---- own gumbel half-0 landed; read u4; launch half-1 ----
    asm volatile("s_waitcnt vmcnt(0)" ::: "memory");
    __builtin_amdgcn_sched_barrier(0);
    f32x4 u4[4];
#pragma unroll
    for (int q = 0; q < 4; ++q)
        u4[q] = *reinterpret_cast<const f32x4*>(
            &greg[rowc * 32 + ((2 * q + hi) ^ (rowc & 7)) * 4]);
    asm volatile("s_waitcnt lgkmcnt(0)" ::: "memory");
    __builtin_amdgcn_sched_barrier(0);
#pragma unroll
    for (int d = 0; d < 4; ++d) {
        const int rr = d * 8 + (lane >> 3);
        dma16(gum + (size_t)(row0 + rr) * VV + (w * 2 + 1) * 32 +
                  4 * ((lane & 7) ^ ((lane >> 3) & 7)),
              &greg[d * 256]);
    }

    // ---- softmax tile0 (no-max; logits bounded) ----
    float ss = 0.f;
#pragma unroll
    for (int r = 0; r < 16; ++r) {
        float u = fminf(fmaxf(u4[r >> 2][r & 3], 1e-10f), 1.0f - 1e-10f);
        float l2u = __builtin_amdgcn_logf(u);
        float t = u - 1.0f;
        float pp = t * (1.0f + t * (-0.5f + t * (0.33333333f + t * (-0.25f + t * 0.2f))));
        float wv = (u >= 0.984375f) ? -pp : (l2u * -0.69314718f);
        float l2w = __builtin_amdgcn_logf(wv);
        float d2 = fmaxf(__builtin_fmaf(-2.0f, acc0[r], x2), 1e-12f);
        float dist = __builtin_amdgcn_sqrtf(d2);
        float lg2 = __builtin_fmaf(-0.72134752f, dist, -0.5f * l2w);
        float e = __builtin_amdgcn_exp2f(lg2);
        acc0[r] = e;
        ss += e;
    }
    // ---- half-1 landed; softmax tile1 ----
    asm volatile("s_waitcnt vmcnt(0)" ::: "memory");
    __builtin_amdgcn_sched_barrier(0);
#pragma unroll
    for (int q = 0; q < 4; ++q)
        u4[q] = *reinterpret_cast<const f32x4*>(
            &greg[rowc * 32 + ((2 * q + hi) ^ (rowc & 7)) * 4]);
#pragma unroll
    for (int r = 0; r < 16; ++r) {
        float u = fminf(fmaxf(u4[r >> 2][r & 3], 1e-10f), 1.0f - 1e-10f);
        float l2u = __builtin_amdgcn_logf(u);
        float t = u - 1.0f;
        float pp = t * (1.0f + t * (-0.5f + t * (0.33333333f + t * (-0.25f + t * 0.2f))));
        float wv = (u >= 0.984375f) ? -pp : (l2u * -0.69314718f);
        float l2w = __builtin_amdgcn_logf(wv);
        float d2 = fmaxf(__builtin_fmaf(-2.0f, acc1[r], x2), 1e-12f);
        float dist = __builtin_amdgcn_sqrtf(d2);
        float lg2 = __builtin_fmaf(-0.72134752f, dist, -0.5f * l2w);
        float e = __builtin_amdgcn_exp2f(lg2);
        acc1[r] = e;
        ss += e;
    }
    ss += __shfl_xor(ss, 32);   // combine hi halves: full sum over wave's 64 v
    if (lane < 32) sred[w * 32 + lane] = ss;
    __syncthreads();   // B1: sred visible (no vmem outstanding)

    float Z = 0.f;
#pragma unroll
    for (int ww = 0; ww < 16; ++ww) Z += sred[ww * 32 + rowc];
    const float rinv = 1.0f / Z;

    // ---- normalize; pb writes (own region: kt in [4w, 4w+4)) ----
    unsigned short* pb = reinterpret_cast<unsigned short*>(gbuf);
#pragma unroll
    for (int q = 0; q < 4; ++q) {
        float p0 = acc0[q * 4 + 0] * rinv, p1 = acc0[q * 4 + 1] * rinv;
        float p2 = acc0[q * 4 + 2] * rinv, p3 = acc0[q * 4 + 3] * rinv;
        acc0[q * 4 + 0] = p0; acc0[q * 4 + 1] = p1;
        acc0[q * 4 + 2] = p2; acc0[q * 4 + 3] = p3;
        uint2 pk;
        __bf16 b0 = (__bf16)p0, b1 = (__bf16)p1, b2 = (__bf16)p2, b3 = (__bf16)p3;
        pk.x = (unsigned int)__builtin_bit_cast(unsigned short, b0) |
               ((unsigned int)__builtin_bit_cast(unsigned short, b1) << 16);
        pk.y = (unsigned int)__builtin_bit_cast(unsigned short, b2) |
               ((unsigned int)__builtin_bit_cast(unsigned short, b3) << 16);
        *reinterpret_cast<uint2*>(
            &pb[(((w * 2) * 2 + (q >> 1)) * 64 + rowc + 32 * (q & 1)) * 8 + 4 * hi]) = pk;
    }
#pragma unroll
    for (int q = 0; q < 4; ++q) {
        float p0 = acc1[q * 4 + 0] * rinv, p1 = acc1[q * 4 + 1] * rinv;
        float p2 = acc1[q * 4 + 2] * rinv, p3 = acc1[q * 4 + 3] * rinv;
        acc1[q * 4 + 0] = p0; acc1[q * 4 + 1] = p1;
        acc1[q * 4 + 2] = p2; acc1[q * 4 + 3] = p3;
        uint2 pk;
        __bf16 b0 = (__bf16)p0, b1 = (__bf16)p1, b2 = (__bf16)p2, b3 = (__bf16)p3;
        pk.x = (unsigned int)__builtin_bit_cast(unsigned short, b0) |
               ((unsigned int)__builtin_bit_cast(unsigned short, b1) << 16);
        pk.y = (unsigned int)__builtin_bit_cast(unsigned short, b2) |
               ((unsigned int)__builtin_bit_cast(unsigned short, b3) << 16);
        *reinterpret_cast<uint2*>(
            &pb[(((w * 2 + 1) * 2 + (q >> 1)) * 64 + rowc + 32 * (q & 1)) * 8 + 4 * hi]) = pk;
    }
    __syncthreads();   // B2: pb tile visible

    // ---- out_p stores (fly under GEMM2) ----
    {
        float* oprow = out_p + (size_t)(row0 + rowc) * VV;
#pragma unroll
        for (int q = 0; q < 4; ++q) {
            const int v0 = (w * 2) * 32 + 8 * q + 4 * hi;
            *reinterpret_cast<float4*>(oprow + v0) =
                (float4){acc0[q * 4 + 0], acc0[q * 4 + 1],
                         acc0[q * 4 + 2], acc0[q * 4 + 3]};
        }
#pragma unroll
        for (int q = 0; q < 4; ++q) {
            const int v0 = (w * 2 + 1) * 32 + 8 * q + 4 * hi;
            *reinterpret_cast<float4*>(oprow + v0) =
                (float4){acc1[q * 4 + 0], acc1[q * 4 + 1],
                         acc1[q * 4 + 2], acc1[q * 4 + 3]};
        }
    }

    // ---- GEMM2: dt = w&7, K-half = w>>3 ----
    const int dt = w & 7, kh = w >> 3;
    f32x16 q2;
#pragma unroll
    for (int i = 0; i < 16; ++i) q2[i] = 0.f;
    const unsigned short* bp = cbB32 + ((size_t)dt * 64 * 64 + lane) * 8;
#pragma unroll
    for (int k2 = 0; k2 < 32; ++k2) {
        const int kt = kh * 32 + k2;
        bf16x8 pA = __builtin_bit_cast(bf16x8,
            *reinterpret_cast<const uint32x4*>(&pb[(kt * 64 + lane) * 8]));
        bf16x8 cbf = __builtin_bit_cast(bf16x8,
            *reinterpret_cast<const uint32x4*>(bp + kt * 512));
        q2 = __builtin_amdgcn_mfma_f32_32x32x16_bf16(pA, cbf, q2, 0, 0, 0);
    }

    if (w >= 8) {
#pragma unroll
        for (int r = 0; r < 16; ++r) {
            const int m = (r & 3) + 8 * (r >> 2) + 4 * hi;
            xq[dt * 1024 + m * 32 + rowc] = q2[r];
        }
    }
    __syncthreads();   // B3: partials visible (out_p stores long since retired)

    if (w < 8) {
        float* qbase = out_q + (size_t)row0 * DD + dt * 32 + rowc;
#pragma unroll
        for (int r = 0; r < 16; ++r) {
            const int m = (r & 3) + 8 * (r >> 2) + 4 * hi;
            qbase[(size_t)m * DD] = q2[r] + xq[dt * 1024 + m * 32 + rowc];
        }
    }
}

extern "C" void kernel_launch(void* const* d_in, const int* in_sizes, int n_in,
                              void* d_out, int out_size, void* d_ws, size_t ws_size,
                              hipStream_t stream) {
    (void)in_sizes; (void)n_in; (void)out_size; (void)ws_size;
    const float* x   = (const float*)d_in[0];   // [16,4096,256]
    const float* cb  = (const float*)d_in[1];   // [1024,256]
    const float* gum = (const float*)d_in[2];   // [65536,1024]

    const int N = 16 * 4096;
    float* out_q = (float*)d_out;                       // [N][256]
    float* out_p = out_q + (size_t)N * DD;              // [N][1024]

    unsigned short* cbA32 = (unsigned short*)d_ws;              // 544 KB
    unsigned short* cbB32 = cbA32 + (size_t)32 * KCA * 64 * 8;  // 512 KB
    vq_prep_kernel<<<VV, 256, 0, stream>>>(cb, cbA32, cbB32);
    vq_main_kernel<<<N / BN, 1024, 0, stream>>>(x, gum, cbA32, cbB32, out_q, out_p);
}

// Round 22
// 399.650 us; speedup vs baseline: 1.1545x; 1.1233x over previous
//
#include <hip/hip_runtime.h>

typedef __bf16 bf16x8 __attribute__((ext_vector_type(8)));
typedef float f32x4 __attribute__((ext_vector_type(4)));
typedef float f32x16 __attribute__((ext_vector_type(16)));
typedef unsigned int uint32x4 __attribute__((ext_vector_type(4)));

#define DD 256
#define VV 1024
#define BN 32    // rows per block
#define KCA 17   // cbA32 K-tiles of 16: 16 data + 1 (c2 fold)

__device__ __forceinline__ unsigned short f2bf(float f) {
    unsigned int b = __float_as_uint(f);
    b += 0x7FFFu + ((b >> 16) & 1u);
    return (unsigned short)(b >> 16);
}

typedef __attribute__((address_space(3))) unsigned int lds_uint;
typedef __attribute__((address_space(1))) const unsigned int glb_uint;
__device__ __forceinline__ void dma16(const float* g, float* l) {
    __builtin_amdgcn_global_load_lds((glb_uint*)g, (lds_uint*)l, 16, 0, 0);
}

// Prep: 32x32-MFMA fragment-major layouts (verified R21).
// cbA32[vt][kt<17][l][j]: A-frag cb[v=vt*32+(l&31)][d=kt*16+(l>>5)*8+j]; kt=16
//   is the c2 tile (j=0: -c2/2 hi, j=1: lo at l=v&31; else 0).
// cbB32[dt][kt<64][l][j]: B-frag cb[v=kt*16+(l>>5)*8+j][d=dt*32+(l&31)].
__global__ __launch_bounds__(256) void vq_prep_kernel(
    const float* __restrict__ cb,
    unsigned short* __restrict__ cbA32,  // [32][17][64][8]
    unsigned short* __restrict__ cbB32)  // [8][64][64][8]
{
    const int v = blockIdx.x;
    const int t = threadIdx.x;
    float val = cb[(size_t)v * DD + t];
    unsigned short h = f2bf(val);
    cbA32[((size_t)((v >> 5) * KCA + (t >> 4)) * 64 +
           (v & 31) + 32 * ((t >> 3) & 1)) * 8 + (t & 7)] = h;
    cbB32[((size_t)((t >> 5) * 64 + (v >> 4)) * 64 +
           (t & 31) + 32 * ((v >> 3) & 1)) * 8 + (v & 7)] = h;

    float p = val * val;
#pragma unroll
    for (int d = 1; d < 64; d <<= 1) p += __shfl_xor(p, d);
    __shared__ float ps[4];
    if ((t & 63) == 0) ps[t >> 6] = p;
    __syncthreads();
    if (t < 16) {
        float c2 = ps[0] + ps[1] + ps[2] + ps[3];
        float m = -0.5f * c2;
        unsigned short hi = f2bf(m);
        float hif = __uint_as_float((unsigned int)hi << 16);
        unsigned short lo = f2bf(m - hif);
        const size_t tb = (size_t)((v >> 5) * KCA + 16) * 64;
        if (t < 8)
            cbA32[(tb + (v & 31)) * 8 + t] =
                (t == 0) ? hi : ((t == 1) ? lo : (unsigned short)0);
        else
            cbA32[(tb + 32 + (v & 31)) * 8 + (t - 8)] = 0;
    }
}

// Fused main, 32-row blocks, 16 waves, 32x32x16 MFMA.
// Key vs R21: pe stored UNNORMALIZED to pb right after each softmax tile
// (acc dies early -> no spills); GEMM2 scales by rinv in the epilogue;
// out_p reconstructed from pb by waves 8-15 concurrently with GEMM2 (waves
// 0-7). No xq exchange. Codebook VMEM per row halved vs R18 (the R20 wall).
__global__ __launch_bounds__(1024, 4) void vq_main_kernel(
    const float* __restrict__ x,          // [N][D]
    const float* __restrict__ gum,        // [N][V]
    const unsigned short* __restrict__ cbA32,
    const unsigned short* __restrict__ cbB32,
    float* __restrict__ out_q,            // [N][D]
    float* __restrict__ out_p)            // [N][V]
{
    __shared__ __align__(16) unsigned short xb16[16 * 64 * 8];  // 16 KB
    __shared__ __align__(16) float gbuf[16 * 1024];             // 64 KB
    __shared__ __align__(16) unsigned short pb[64 * 64 * 8];    // 64 KB
    __shared__ float sred[16 * 32];                             // 2 KB
    __shared__ float sZ[32];
    __shared__ float sx2[32];

    const int tid  = threadIdx.x;
    const int w    = tid >> 6;     // 0..15
    const int lane = tid & 63;
    const int hi   = lane >> 5;
    const int rowc = lane & 31;
    const int row0 = blockIdx.x * BN;
    float* greg = &gbuf[w * 1024];

    // ---- gumbel DMA phase-0 (v-tile vt = 2w) ----
#pragma unroll
    for (int d = 0; d < 4; ++d) {
        const int rr = d * 8 + (lane >> 3);
        dma16(gum + (size_t)(row0 + rr) * VV + (w * 2) * 32 +
                  4 * ((lane & 7) ^ ((lane >> 3) & 7)),
              &greg[d * 256]);
    }

    // ---- x load -> xb16 (B-frag layout) + x2 ----
    {
        const int xr = tid >> 5;   // 0..31
        const int c  = tid & 31;
        const float* xp = x + (size_t)(row0 + xr) * DD + c * 8;
        f32x4 a = *reinterpret_cast<const f32x4*>(xp);
        f32x4 b = *reinterpret_cast<const f32x4*>(xp + 4);
        float s = 0.f;
        bf16x8 fr;
#pragma unroll
        for (int j = 0; j < 4; ++j) {
            s += a[j] * a[j] + b[j] * b[j];
            fr[j]     = (__bf16)a[j];
            fr[j + 4] = (__bf16)b[j];
        }
#pragma unroll
        for (int d = 1; d < 32; d <<= 1) s += __shfl_xor(s, d);
        if ((lane & 31) == 0) sx2[xr] = s;
        *reinterpret_cast<uint32x4*>(
            &xb16[((c >> 1) * 64 + xr + 32 * (c & 1)) * 8]) =
            __builtin_bit_cast(uint32x4, fr);
    }
    asm volatile("s_waitcnt lgkmcnt(0)" ::: "memory");
    __builtin_amdgcn_sched_barrier(0);
    __builtin_amdgcn_s_barrier();   // B0: xb16 + sx2 visible; DMA in flight

    // ---- GEMM1: acc_t (t=0,1) = S[32 rows][vt=2w+t], K=272 ----
    f32x16 acc0, acc1;
#pragma unroll
    for (int i = 0; i < 16; ++i) { acc0[i] = 0.f; acc1[i] = 0.f; }
    const unsigned short* apA = cbA32 + ((size_t)(w * 2) * KCA * 64 + lane) * 8;
#pragma unroll
    for (int kt = 0; kt < 16; ++kt) {
        bf16x8 bfr = __builtin_bit_cast(bf16x8,
            *reinterpret_cast<const uint32x4*>(&xb16[(kt * 64 + lane) * 8]));
        bf16x8 c0 = __builtin_bit_cast(bf16x8,
            *reinterpret_cast<const uint32x4*>(apA + kt * 512));
        bf16x8 c1 = __builtin_bit_cast(bf16x8,
            *reinterpret_cast<const uint32x4*>(apA + KCA * 512 + kt * 512));
        acc0 = __builtin_amdgcn_mfma_f32_32x32x16_bf16(c0, bfr, acc0, 0, 0, 0);
        acc1 = __builtin_amdgcn_mfma_f32_32x32x16_bf16(c1, bfr, acc1, 0, 0, 0);
    }
    {   // c2 tile (kt=16)
        uint32x4 wv = {0u, 0u, 0u, 0u};
        if (hi == 0) wv[0] = 0x3F803F80u;
        bf16x8 bfr = __builtin_bit_cast(bf16x8, wv);
        bf16x8 c0 = __builtin_bit_cast(bf16x8,
            *reinterpret_cast<const uint32x4*>(apA + 16 * 512));
        bf16x8 c1 = __builtin_bit_cast(bf16x8,
            *reinterpret_cast<const uint32x4*>(apA + KCA * 512 + 16 * 512));
        acc0 = __builtin_amdgcn_mfma_f32_32x32x16_bf16(c0, bfr, acc0, 0, 0, 0);
        acc1 = __builtin_amdgcn_mfma_f32_32x32x16_bf16(c1, bfr, acc1, 0, 0, 0);
    }

    const float x2 = sx2[rowc];

    // ---- phase-0 landed; read u4; launch phase-1 DMA ----
    asm volatile("s_waitcnt vmcnt(0)" ::: "memory");
    __builtin_amdgcn_sched_barrier(0);
    f32x4 u4[4];
#pragma unroll
    for (int q = 0; q < 4; ++q)
        u4[q] = *reinterpret_cast<const f32x4*>(
            &greg[rowc * 32 + ((2 * q + hi) ^ (rowc & 7)) * 4]);
    asm volatile("s_waitcnt lgkmcnt(0)" ::: "memory");
    __builtin_amdgcn_sched_barrier(0);
#pragma unroll
    for (int d = 0; d < 4; ++d) {
        const int rr = d * 8 + (lane >> 3);
        dma16(gum + (size_t)(row0 + rr) * VV + (w * 2 + 1) * 32 +
                  4 * ((lane & 7) ^ ((lane >> 3) & 7)),
              &greg[d * 256]);
    }

    // ---- softmax tile0 (no-max) -> pb UNNORMALIZED; acc0 dies here ----
    float ss = 0.f;
#pragma unroll
    for (int r = 0; r < 16; ++r) {
        float u = fminf(fmaxf(u4[r >> 2][r & 3], 1e-10f), 1.0f - 1e-10f);
        float l2u = __builtin_amdgcn_logf(u);
        float t = u - 1.0f;
        float pp = t * (1.0f + t * (-0.5f + t * (0.33333333f + t * (-0.25f + t * 0.2f))));
        float wv = (u >= 0.984375f) ? -pp : (l2u * -0.69314718f);
        float l2w = __builtin_amdgcn_logf(wv);
        float d2 = fmaxf(__builtin_fmaf(-2.0f, acc0[r], x2), 1e-12f);
        float dist = __builtin_amdgcn_sqrtf(d2);
        float lg2 = __builtin_fmaf(-0.72134752f, dist, -0.5f * l2w);
        float e = __builtin_amdgcn_exp2f(lg2);
        acc0[r] = e;
        ss += e;
    }
#pragma unroll
    for (int q = 0; q < 4; ++q) {
        uint2 pk;
        __bf16 b0 = (__bf16)acc0[q * 4 + 0], b1 = (__bf16)acc0[q * 4 + 1];
        __bf16 b2 = (__bf16)acc0[q * 4 + 2], b3 = (__bf16)acc0[q * 4 + 3];
        pk.x = (unsigned int)__builtin_bit_cast(unsigned short, b0) |
               ((unsigned int)__builtin_bit_cast(unsigned short, b1) << 16);
        pk.y = (unsigned int)__builtin_bit_cast(unsigned short, b2) |
               ((unsigned int)__builtin_bit_cast(unsigned short, b3) << 16);
        *reinterpret_cast<uint2*>(
            &pb[(((w * 2) * 2 + (q >> 1)) * 64 + rowc + 32 * (q & 1)) * 8 + 4 * hi]) = pk;
    }

    // ---- phase-1 landed; softmax tile1 -> pb; acc1 dies here ----
    asm volatile("s_waitcnt vmcnt(0)" ::: "memory");
    __builtin_amdgcn_sched_barrier(0);
#pragma unroll
    for (int q = 0; q < 4; ++q)
        u4[q] = *reinterpret_cast<const f32x4*>(
            &greg[rowc * 32 + ((2 * q + hi) ^ (rowc & 7)) * 4]);
#pragma unroll
    for (int r = 0; r < 16; ++r) {
        float u = fminf(fmaxf(u4[r >> 2][r & 3], 1e-10f), 1.0f - 1e-10f);
        float l2u = __builtin_amdgcn_logf(u);
        float t = u - 1.0f;
        float pp = t * (1.0f + t * (-0.5f + t * (0.33333333f + t * (-0.25f + t * 0.2f))));
        float wv = (u >= 0.984375f) ? -pp : (l2u * -0.69314718f);
        float l2w = __builtin_amdgcn_logf(wv);
        float d2 = fmaxf(__builtin_fmaf(-2.0f, acc1[r], x2), 1e-12f);
        float dist = __builtin_amdgcn_sqrtf(d2);
        float lg2 = __builtin_fmaf(-0.72134752f, dist, -0.5f * l2w);
        float e = __builtin_amdgcn_exp2f(lg2);
        acc1[r] = e;
        ss += e;
    }
#pragma unroll
    for (int q = 0; q < 4; ++q) {
        uint2 pk;
        __bf16 b0 = (__bf16)acc1[q * 4 + 0], b1 = (__bf16)acc1[q * 4 + 1];
        __bf16 b2 = (__bf16)acc1[q * 4 + 2], b3 = (__bf16)acc1[q * 4 + 3];
        pk.x = (unsigned int)__builtin_bit_cast(unsigned short, b0) |
               ((unsigned int)__builtin_bit_cast(unsigned short, b1) << 16);
        pk.y = (unsigned int)__builtin_bit_cast(unsigned short, b2) |
               ((unsigned int)__builtin_bit_cast(unsigned short, b3) << 16);
        *reinterpret_cast<uint2*>(
            &pb[(((w * 2 + 1) * 2 + (q >> 1)) * 64 + rowc + 32 * (q & 1)) * 8 + 4 * hi]) = pk;
    }

    ss += __shfl_xor(ss, 32);
    if (lane < 32) sred[w * 32 + lane] = ss;
    __syncthreads();   // B1: sred + pb visible

    if (tid < 32) {
        float Z = 0.f;
#pragma unroll
        for (int ww = 0; ww < 16; ++ww) Z += sred[ww * 32 + tid];
        sZ[tid] = 1.0f / Z;
    }
    __syncthreads();   // B2: sZ visible

    if (w < 8) {
        // ---- GEMM2 (unnormalized P): dt = w, full K; scale by rinv[m] ----
        const int dt = w;
        f32x16 q2;
#pragma unroll
        for (int i = 0; i < 16; ++i) q2[i] = 0.f;
        const unsigned short* bp = cbB32 + ((size_t)dt * 64 * 64 + lane) * 8;
#pragma unroll
        for (int kt = 0; kt < 64; ++kt) {
            bf16x8 pA = __builtin_bit_cast(bf16x8,
                *reinterpret_cast<const uint32x4*>(&pb[(kt * 64 + lane) * 8]));
            bf16x8 cbf = __builtin_bit_cast(bf16x8,
                *reinterpret_cast<const uint32x4*>(bp + kt * 512));
            q2 = __builtin_amdgcn_mfma_f32_32x32x16_bf16(pA, cbf, q2, 0, 0, 0);
        }
        float* qbase = out_q + (size_t)row0 * DD + dt * 32 + rowc;
#pragma unroll
        for (int r = 0; r < 16; ++r) {
            const int m = (r & 3) + 8 * (r >> 2) + 4 * hi;
            qbase[(size_t)m * DD] = q2[r] * sZ[m];
        }
    } else {
        // ---- out_p from pb (x rinv), 4 rows per wave, coalesced f32x4 ----
        const int row = (w - 8) * 4 + (lane >> 4);
        const float rinv = sZ[row];
        float* oprow = out_p + (size_t)(row0 + row) * VV;
#pragma unroll
        for (int c = 0; c < 16; ++c) {
            const int v0 = c * 64 + (lane & 15) * 4;
            const int kt = v0 >> 4;
            const int sub = (v0 >> 3) & 1;
            const int j0 = v0 & 7;
            uint2 pk = *reinterpret_cast<const uint2*>(
                &pb[((kt * 64) + row + 32 * sub) * 8 + j0]);
            float o0 = __uint_as_float(pk.x << 16) * rinv;
            float o1 = __uint_as_float(pk.x & 0xFFFF0000u) * rinv;
            float o2 = __uint_as_float(pk.y << 16) * rinv;
            float o3 = __uint_as_float(pk.y & 0xFFFF0000u) * rinv;
            *reinterpret_cast<float4*>(oprow + v0) = (float4){o0, o1, o2, o3};
        }
    }
}

extern "C" void kernel_launch(void* const* d_in, const int* in_sizes, int n_in,
                              void* d_out, int out_size, void* d_ws, size_t ws_size,
                              hipStream_t stream) {
    (void)in_sizes; (void)n_in; (void)out_size; (void)ws_size;
    const float* x   = (const float*)d_in[0];   // [16,4096,256]
    const float* cb  = (const float*)d_in[1];   // [1024,256]
    const float* gum = (const float*)d_in[2];   // [65536,1024]

    const int N = 16 * 4096;
    float* out_q = (float*)d_out;                       // [N][256]
    float* out_p = out_q + (size_t)N * DD;              // [N][1024]

    unsigned short* cbA32 = (unsigned short*)d_ws;              // 544 KB
    unsigned short* cbB32 = cbA32 + (size_t)32 * KCA * 64 * 8;  // 512 KB
    vq_prep_kernel<<<VV, 256, 0, stream>>>(cb, cbA32, cbB32);
    vq_main_kernel<<<N / BN, 1024, 0, stream>>>(x, gum, cbA32, cbB32, out_q, out_p);
}

// Round 23
// 232.637 us; speedup vs baseline: 1.9833x; 1.7179x over previous
//
#include <hip/hip_runtime.h>

typedef __bf16 bf16x8 __attribute__((ext_vector_type(8)));
typedef float f32x4 __attribute__((ext_vector_type(4)));
typedef float f32x16 __attribute__((ext_vector_type(16)));
typedef unsigned int uint32x4 __attribute__((ext_vector_type(4)));

#define DD 256
#define VV 1024
#define BN 32    // rows per block
#define KCA 17   // cbA32 K-tiles of 16: 16 data + 1 (c2 fold)

__device__ __forceinline__ unsigned short f2bf(float f) {
    unsigned int b = __float_as_uint(f);
    b += 0x7FFFu + ((b >> 16) & 1u);
    return (unsigned short)(b >> 16);
}

typedef __attribute__((address_space(3))) unsigned int lds_uint;
typedef __attribute__((address_space(1))) const unsigned int glb_uint;
__device__ __forceinline__ void dma16(const float* g, float* l) {
    __builtin_amdgcn_global_load_lds((glb_uint*)g, (lds_uint*)l, 16, 0, 0);
}

// Prep: 32x32-MFMA fragment-major layouts (verified R21/R22).
// cbA32[vt][kt<17][l][j]: A-frag cb[v=vt*32+(l&31)][d=kt*16+(l>>5)*8+j]; kt=16
//   is the c2 tile (j=0: -c2/2 hi, j=1: lo at l=v&31; else 0).
// cbB32[dt][kt<64][l][j]: B-frag cb[v=kt*16+(l>>5)*8+j][d=dt*32+(l&31)].
__global__ __launch_bounds__(256) void vq_prep_kernel(
    const float* __restrict__ cb,
    unsigned short* __restrict__ cbA32,  // [32][17][64][8]
    unsigned short* __restrict__ cbB32)  // [8][64][64][8]
{
    const int v = blockIdx.x;
    const int t = threadIdx.x;
    float val = cb[(size_t)v * DD + t];
    unsigned short h = f2bf(val);
    cbA32[((size_t)((v >> 5) * KCA + (t >> 4)) * 64 +
           (v & 31) + 32 * ((t >> 3) & 1)) * 8 + (t & 7)] = h;
    cbB32[((size_t)((t >> 5) * 64 + (v >> 4)) * 64 +
           (t & 31) + 32 * ((v >> 3) & 1)) * 8 + (v & 7)] = h;

    float p = val * val;
#pragma unroll
    for (int d = 1; d < 64; d <<= 1) p += __shfl_xor(p, d);
    __shared__ float ps[4];
    if ((t & 63) == 0) ps[t >> 6] = p;
    __syncthreads();
    if (t < 16) {
        float c2 = ps[0] + ps[1] + ps[2] + ps[3];
        float m = -0.5f * c2;
        unsigned short hi = f2bf(m);
        float hif = __uint_as_float((unsigned int)hi << 16);
        unsigned short lo = f2bf(m - hif);
        const size_t tb = (size_t)((v >> 5) * KCA + 16) * 64;
        if (t < 8)
            cbA32[(tb + (v & 31)) * 8 + t] =
                (t == 0) ? hi : ((t == 1) ? lo : (unsigned short)0);
        else
            cbA32[(tb + 32 + (v & 31)) * 8 + (t - 8)] = 0;
    }
}

// Fused main, 32-row blocks, 16 waves, 32x32x16 MFMA.
// vs R22: GEMM1's two v-tiles processed SEQUENTIALLY -> only ONE f32x16
// accumulator live at any time (peak live ~70 regs, no spills by
// construction). pb holds UNNORMALIZED bf16 P; GEMM2 scales by rinv in
// epilogue; waves 8-15 write out_p concurrently with waves 0-7's GEMM2.
__global__ __launch_bounds__(1024, 4) void vq_main_kernel(
    const float* __restrict__ x,          // [N][D]
    const float* __restrict__ gum,        // [N][V]
    const unsigned short* __restrict__ cbA32,
    const unsigned short* __restrict__ cbB32,
    float* __restrict__ out_q,            // [N][D]
    float* __restrict__ out_p)            // [N][V]
{
    __shared__ __align__(16) unsigned short xb16[16 * 64 * 8];  // 16 KB
    __shared__ __align__(16) float gbuf[16 * 1024];             // 64 KB
    __shared__ __align__(16) unsigned short pb[64 * 64 * 8];    // 64 KB
    __shared__ float sred[16 * 32];                             // 2 KB
    __shared__ float sZ[32];
    __shared__ float sx2[32];

    const int tid  = threadIdx.x;
    const int w    = tid >> 6;     // 0..15
    const int lane = tid & 63;
    const int hi   = lane >> 5;
    const int rowc = lane & 31;
    const int row0 = blockIdx.x * BN;
    float* greg = &gbuf[w * 1024];

    // ---- gumbel DMA tile0 (v-tile vt = 2w) ----
#pragma unroll
    for (int d = 0; d < 4; ++d) {
        const int rr = d * 8 + (lane >> 3);
        dma16(gum + (size_t)(row0 + rr) * VV + (w * 2) * 32 +
                  4 * ((lane & 7) ^ ((lane >> 3) & 7)),
              &greg[d * 256]);
    }

    // ---- x load -> xb16 (B-frag layout) + x2 ----
    {
        const int xr = tid >> 5;   // 0..31
        const int c  = tid & 31;
        const float* xp = x + (size_t)(row0 + xr) * DD + c * 8;
        f32x4 a = *reinterpret_cast<const f32x4*>(xp);
        f32x4 b = *reinterpret_cast<const f32x4*>(xp + 4);
        float s = 0.f;
        bf16x8 fr;
#pragma unroll
        for (int j = 0; j < 4; ++j) {
            s += a[j] * a[j] + b[j] * b[j];
            fr[j]     = (__bf16)a[j];
            fr[j + 4] = (__bf16)b[j];
        }
#pragma unroll
        for (int d = 1; d < 32; d <<= 1) s += __shfl_xor(s, d);
        if ((lane & 31) == 0) sx2[xr] = s;
        *reinterpret_cast<uint32x4*>(
            &xb16[((c >> 1) * 64 + xr + 32 * (c & 1)) * 8]) =
            __builtin_bit_cast(uint32x4, fr);
    }
    asm volatile("s_waitcnt lgkmcnt(0)" ::: "memory");
    __builtin_amdgcn_sched_barrier(0);
    __builtin_amdgcn_s_barrier();   // B0: xb16 + sx2 visible; DMA in flight

    const float x2 = sx2[rowc];
    const unsigned short* apA = cbA32 + ((size_t)(w * 2) * KCA * 64 + lane) * 8;
    float ss = 0.f;
    f32x16 acc;

    // ================== TILE 0 ==================
#pragma unroll
    for (int i = 0; i < 16; ++i) acc[i] = 0.f;
#pragma unroll
    for (int kt = 0; kt < 16; ++kt) {
        bf16x8 bfr = __builtin_bit_cast(bf16x8,
            *reinterpret_cast<const uint32x4*>(&xb16[(kt * 64 + lane) * 8]));
        bf16x8 c0 = __builtin_bit_cast(bf16x8,
            *reinterpret_cast<const uint32x4*>(apA + kt * 512));
        acc = __builtin_amdgcn_mfma_f32_32x32x16_bf16(c0, bfr, acc, 0, 0, 0);
    }
    {   // c2 tile (kt=16)
        uint32x4 wv = {0u, 0u, 0u, 0u};
        if (hi == 0) wv[0] = 0x3F803F80u;
        bf16x8 bfr = __builtin_bit_cast(bf16x8, wv);
        bf16x8 c0 = __builtin_bit_cast(bf16x8,
            *reinterpret_cast<const uint32x4*>(apA + 16 * 512));
        acc = __builtin_amdgcn_mfma_f32_32x32x16_bf16(c0, bfr, acc, 0, 0, 0);
    }

    // tile0 gumbel landed; read u4; free region; issue tile1 DMA
    asm volatile("s_waitcnt vmcnt(0)" ::: "memory");
    __builtin_amdgcn_sched_barrier(0);
    {
        f32x4 u4[4];
#pragma unroll
        for (int q = 0; q < 4; ++q)
            u4[q] = *reinterpret_cast<const f32x4*>(
                &greg[rowc * 32 + ((2 * q + hi) ^ (rowc & 7)) * 4]);
        asm volatile("s_waitcnt lgkmcnt(0)" ::: "memory");
        __builtin_amdgcn_sched_barrier(0);
#pragma unroll
        for (int d = 0; d < 4; ++d) {
            const int rr = d * 8 + (lane >> 3);
            dma16(gum + (size_t)(row0 + rr) * VV + (w * 2 + 1) * 32 +
                      4 * ((lane & 7) ^ ((lane >> 3) & 7)),
                  &greg[d * 256]);
        }

        // softmax tile0 (no-max) -> pb UNNORMALIZED; acc dies after
#pragma unroll
        for (int r = 0; r < 16; ++r) {
            float u = fminf(fmaxf(u4[r >> 2][r & 3], 1e-10f), 1.0f - 1e-10f);
            float l2u = __builtin_amdgcn_logf(u);
            float t = u - 1.0f;
            float pp = t * (1.0f + t * (-0.5f + t * (0.33333333f + t * (-0.25f + t * 0.2f))));
            float wv = (u >= 0.984375f) ? -pp : (l2u * -0.69314718f);
            float l2w = __builtin_amdgcn_logf(wv);
            float d2 = fmaxf(__builtin_fmaf(-2.0f, acc[r], x2), 1e-12f);
            float dist = __builtin_amdgcn_sqrtf(d2);
            float lg2 = __builtin_fmaf(-0.72134752f, dist, -0.5f * l2w);
            float e = __builtin_amdgcn_exp2f(lg2);
            acc[r] = e;
            ss += e;
        }
#pragma unroll
        for (int q = 0; q < 4; ++q) {
            uint2 pk;
            __bf16 b0 = (__bf16)acc[q * 4 + 0], b1 = (__bf16)acc[q * 4 + 1];
            __bf16 b2 = (__bf16)acc[q * 4 + 2], b3 = (__bf16)acc[q * 4 + 3];
            pk.x = (unsigned int)__builtin_bit_cast(unsigned short, b0) |
                   ((unsigned int)__builtin_bit_cast(unsigned short, b1) << 16);
            pk.y = (unsigned int)__builtin_bit_cast(unsigned short, b2) |
                   ((unsigned int)__builtin_bit_cast(unsigned short, b3) << 16);
            *reinterpret_cast<uint2*>(
                &pb[(((w * 2) * 2 + (q >> 1)) * 64 + rowc + 32 * (q & 1)) * 8 + 4 * hi]) = pk;
        }
    }

    // ================== TILE 1 ==================
#pragma unroll
    for (int i = 0; i < 16; ++i) acc[i] = 0.f;
#pragma unroll
    for (int kt = 0; kt < 16; ++kt) {
        bf16x8 bfr = __builtin_bit_cast(bf16x8,
            *reinterpret_cast<const uint32x4*>(&xb16[(kt * 64 + lane) * 8]));
        bf16x8 c1 = __builtin_bit_cast(bf16x8,
            *reinterpret_cast<const uint32x4*>(apA + KCA * 512 + kt * 512));
        acc = __builtin_amdgcn_mfma_f32_32x32x16_bf16(c1, bfr, acc, 0, 0, 0);
    }
    {   // c2 tile
        uint32x4 wv = {0u, 0u, 0u, 0u};
        if (hi == 0) wv[0] = 0x3F803F80u;
        bf16x8 bfr = __builtin_bit_cast(bf16x8, wv);
        bf16x8 c1 = __builtin_bit_cast(bf16x8,
            *reinterpret_cast<const uint32x4*>(apA + KCA * 512 + 16 * 512));
        acc = __builtin_amdgcn_mfma_f32_32x32x16_bf16(c1, bfr, acc, 0, 0, 0);
    }

    // tile1 gumbel landed (DMA hid under GEMM1 tile1)
    asm volatile("s_waitcnt vmcnt(0)" ::: "memory");
    __builtin_amdgcn_sched_barrier(0);
    {
        f32x4 u4[4];
#pragma unroll
        for (int q = 0; q < 4; ++q)
            u4[q] = *reinterpret_cast<const f32x4*>(
                &greg[rowc * 32 + ((2 * q + hi) ^ (rowc & 7)) * 4]);
#pragma unroll
        for (int r = 0; r < 16; ++r) {
            float u = fminf(fmaxf(u4[r >> 2][r & 3], 1e-10f), 1.0f - 1e-10f);
            float l2u = __builtin_amdgcn_logf(u);
            float t = u - 1.0f;
            float pp = t * (1.0f + t * (-0.5f + t * (0.33333333f + t * (-0.25f + t * 0.2f))));
            float wv = (u >= 0.984375f) ? -pp : (l2u * -0.69314718f);
            float l2w = __builtin_amdgcn_logf(wv);
            float d2 = fmaxf(__builtin_fmaf(-2.0f, acc[r], x2), 1e-12f);
            float dist = __builtin_amdgcn_sqrtf(d2);
            float lg2 = __builtin_fmaf(-0.72134752f, dist, -0.5f * l2w);
            float e = __builtin_amdgcn_exp2f(lg2);
            acc[r] = e;
            ss += e;
        }
#pragma unroll
        for (int q = 0; q < 4; ++q) {
            uint2 pk;
            __bf16 b0 = (__bf16)acc[q * 4 + 0], b1 = (__bf16)acc[q * 4 + 1];
            __bf16 b2 = (__bf16)acc[q * 4 + 2], b3 = (__bf16)acc[q * 4 + 3];
            pk.x = (unsigned int)__builtin_bit_cast(unsigned short, b0) |
                   ((unsigned int)__builtin_bit_cast(unsigned short, b1) << 16);
            pk.y = (unsigned int)__builtin_bit_cast(unsigned short, b2) |
                   ((unsigned int)__builtin_bit_cast(unsigned short, b3) << 16);
            *reinterpret_cast<uint2*>(
                &pb[(((w * 2 + 1) * 2 + (q >> 1)) * 64 + rowc + 32 * (q & 1)) * 8 + 4 * hi]) = pk;
        }
    }

    ss += __shfl_xor(ss, 32);
    if (lane < 32) sred[w * 32 + lane] = ss;
    __syncthreads();   // B1: sred + pb visible

    if (tid < 32) {
        float Z = 0.f;
#pragma unroll
        for (int ww = 0; ww < 16; ++ww) Z += sred[ww * 32 + tid];
        sZ[tid] = 1.0f / Z;
    }
    __syncthreads();   // B2: sZ visible

    if (w < 8) {
        // ---- GEMM2 (unnormalized P): dt = w, full K; scale by rinv[m] ----
        const int dt = w;
        f32x16 q2;
#pragma unroll
        for (int i = 0; i < 16; ++i) q2[i] = 0.f;
        const unsigned short* bp = cbB32 + ((size_t)dt * 64 * 64 + lane) * 8;
#pragma unroll
        for (int kt = 0; kt < 64; ++kt) {
            bf16x8 pA = __builtin_bit_cast(bf16x8,
                *reinterpret_cast<const uint32x4*>(&pb[(kt * 64 + lane) * 8]));
            bf16x8 cbf = __builtin_bit_cast(bf16x8,
                *reinterpret_cast<const uint32x4*>(bp + kt * 512));
            q2 = __builtin_amdgcn_mfma_f32_32x32x16_bf16(pA, cbf, q2, 0, 0, 0);
        }
        float* qbase = out_q + (size_t)row0 * DD + dt * 32 + rowc;
#pragma unroll
        for (int r = 0; r < 16; ++r) {
            const int m = (r & 3) + 8 * (r >> 2) + 4 * hi;
            qbase[(size_t)m * DD] = q2[r] * sZ[m];
        }
    } else {
        // ---- out_p from pb (x rinv), 4 rows per wave, coalesced f32x4 ----
        const int row = (w - 8) * 4 + (lane >> 4);
        const float rinv = sZ[row];
        float* oprow = out_p + (size_t)(row0 + row) * VV;
#pragma unroll
        for (int c = 0; c < 16; ++c) {
            const int v0 = c * 64 + (lane & 15) * 4;
            const int kt = v0 >> 4;
            const int sub = (v0 >> 3) & 1;
            const int j0 = v0 & 7;
            uint2 pk = *reinterpret_cast<const uint2*>(
                &pb[((kt * 64) + row + 32 * sub) * 8 + j0]);
            float o0 = __uint_as_float(pk.x << 16) * rinv;
            float o1 = __uint_as_float(pk.x & 0xFFFF0000u) * rinv;
            float o2 = __uint_as_float(pk.y << 16) * rinv;
            float o3 = __uint_as_float(pk.y & 0xFFFF0000u) * rinv;
            *reinterpret_cast<float4*>(oprow + v0) = (float4){o0, o1, o2, o3};
        }
    }
}

extern "C" void kernel_launch(void* const* d_in, const int* in_sizes, int n_in,
                              void* d_out, int out_size, void* d_ws, size_t ws_size,
                              hipStream_t stream) {
    (void)in_sizes; (void)n_in; (void)out_size; (void)ws_size;
    const float* x   = (const float*)d_in[0];   // [16,4096,256]
    const float* cb  = (const float*)d_in[1];   // [1024,256]
    const float* gum = (const float*)d_in[2];   // [65536,1024]

    const int N = 16 * 4096;
    float* out_q = (float*)d_out;                       // [N][256]
    float* out_p = out_q + (size_t)N * DD;              // [N][1024]

    unsigned short* cbA32 = (unsigned short*)d_ws;              // 544 KB
    unsigned short* cbB32 = cbA32 + (size_t)32 * KCA * 64 * 8;  // 512 KB
    vq_prep_kernel<<<VV, 256, 0, stream>>>(cb, cbA32, cbB32);
    vq_main_kernel<<<N / BN, 1024, 0, stream>>>(x, gum, cbA32, cbB32, out_q, out_p);
}